// Round 9
// baseline (32.830 us; speedup 1.0000x reference)
//
#include <hip/hip_runtime.h>
#include <hip/hip_fp16.h>

// scores[r,t] = b2 + sum_h W2[h] * relu(rp[r,h] + tp[t,h])
// SINGLE dispatch (per-dispatch overhead ~7.2us dominated the 2-kernel split).
// Grid (16,16) x 512 thr, 1 block/CU. Block = 32r x 32t output tile.
// Each block recomputes its own rp/tp strips (W1 re-read ~1MB/CU from L2),
// pipelined over 8 h-chunks of 64:
//   stage(regs->Ws f16 transposed swizzled) + prefetch next chunk -> barrier ->
//   MFMA (A=W1^T from LDS, B=X rows in regs) + bias + pack half2 -> barrier ->
//   score-accumulate (v_pk_add/max_f16 + v_dot2_f32_f16).
// No cooperative launch (R6 deadlock), no atomics, deterministic.

#define RT 512
#define DD 256
#define HD 512

typedef _Float16 h2 __attribute__((ext_vector_type(2)));
typedef _Float16 h8 __attribute__((ext_vector_type(8)));
typedef float f32x4 __attribute__((ext_vector_type(4)));

__device__ inline unsigned h2u(h2 v) { return __builtin_bit_cast(unsigned, v); }
__device__ inline h2 u2h(unsigned u) { return __builtin_bit_cast(h2, u); }
__device__ inline h2 pk(float a, float b) {
    return __builtin_bit_cast(h2, __builtin_amdgcn_cvt_pkrtz(a, b));
}
__device__ inline unsigned pku(float a, float b) { return h2u(pk(a, b)); }

__global__ __launch_bounds__(512) void fused(
    const float* __restrict__ robot, const float* __restrict__ task,
    const float* __restrict__ W1, const float* __restrict__ b1,
    const float* __restrict__ W2, const float* __restrict__ b2,
    float* __restrict__ out)
{
    __shared__ __attribute__((aligned(16))) unsigned char smem[73728];
    // [0, 65536):     Ws f16 [2 z][64 h][256 k], rows 512B, XOR swz ((h&7)<<4)
    // [65536, 69632): rs uint [32 hp][32 r]   (packed half2 h-pairs)
    // [69632, 73728): ts uint [32 hp][32 t]
    unsigned* rs = (unsigned*)(smem + 65536);
    unsigned* ts = (unsigned*)(smem + 69632);

    const int tid = threadIdx.x;
    const int wave = tid >> 6, lane = tid & 63;
    const int rbase = blockIdx.y * 32, tbase = blockIdx.x * 32;

    const int wz = wave & 1;            // 0 = robot/rp side, 1 = task/tp side
    const int hstrip = wave >> 1;       // 16-h strip within the 64-h chunk
    const int lm = lane & 15, lq = lane >> 4;

    // ---- prologue: B fragments (X rows, full K) in registers, f32->f16 ----
    const float* X = wz ? task : robot;
    const int xbase = wz ? tbase : rbase;
    uint4 breg[2][8];
    #pragma unroll
    for (int f = 0; f < 2; ++f) {
        const float* xp = &X[(xbase + f * 16 + lm) * DD + lq * 8];
        #pragma unroll
        for (int ks = 0; ks < 8; ++ks) {
            float4 p0 = *(const float4*)(xp + ks * 32);
            float4 p1 = *(const float4*)(xp + ks * 32 + 4);
            breg[f][ks] = make_uint4(pku(p0.x, p0.y), pku(p0.z, p0.w),
                                     pku(p1.x, p1.y), pku(p1.z, p1.w));
        }
    }

    // ---- W1 prefetch mapping: thread covers h-quad hq*4..+3, k-rows kg*8..+7 ----
    const int hq = tid & 15;
    const int kg = tid >> 4;            // 0..31
    float4 wreg[2][8];
    #pragma unroll
    for (int z = 0; z < 2; ++z)
        #pragma unroll
        for (int u = 0; u < 8; ++u)
            wreg[z][u] = *(const float4*)&W1[(z * DD + kg * 8 + u) * HD + hq * 4];

    float sacc[4][4] = {};
    const int ly = (lane >> 3) & 7, lx = lane & 7;
    const h2 hzero = {};

    #pragma unroll 1
    for (int it = 0; it < 8; ++it) {
        const int hc = it * 64;

        // ---- stage: wreg -> Ws (f16, [h][k] transposed, swizzled) ----
        #pragma unroll
        for (int z = 0; z < 2; ++z) {
            const float4 w0 = wreg[z][0], w1 = wreg[z][1], w2v = wreg[z][2], w3 = wreg[z][3];
            const float4 w4 = wreg[z][4], w5 = wreg[z][5], w6 = wreg[z][6], w7 = wreg[z][7];
            #define STG(HH2, C) { \
                int h = hq * 4 + HH2; \
                uint4 o = make_uint4(pku(w0.C, w1.C), pku(w2v.C, w3.C), \
                                     pku(w4.C, w5.C), pku(w6.C, w7.C)); \
                *(uint4*)(smem + z * 32768 + ((h * 512 + kg * 16) ^ ((h & 7) << 4))) = o; }
            STG(0, x) STG(1, y) STG(2, z) STG(3, w)
            #undef STG
        }
        // issue next chunk's global loads (overlap with MFMA+score below)
        if (it < 7) {
            const int hcn = hc + 64;
            #pragma unroll
            for (int z = 0; z < 2; ++z)
                #pragma unroll
                for (int u = 0; u < 8; ++u)
                    wreg[z][u] = *(const float4*)&W1[(z * DD + kg * 8 + u) * HD + hcn + hq * 4];
        }
        __syncthreads();

        // ---- MFMA: wave computes [16 h][32 r] of side wz ----
        f32x4 acc0 = {0.f, 0.f, 0.f, 0.f}, acc1 = {0.f, 0.f, 0.f, 0.f};
        const int h0 = hstrip * 16;
        #pragma unroll
        for (int ks = 0; ks < 8; ++ks) {
            int ha = h0 + lm;
            h8 a = *(const h8*)(smem + wz * 32768 +
                                ((ha * 512 + ks * 64 + lq * 16) ^ ((ha & 7) << 4)));
            acc0 = __builtin_amdgcn_mfma_f32_16x16x32_f16(a, __builtin_bit_cast(h8, breg[0][ks]), acc0, 0, 0, 0);
            acc1 = __builtin_amdgcn_mfma_f32_16x16x32_f16(a, __builtin_bit_cast(h8, breg[1][ks]), acc1, 0, 0, 0);
        }
        // bias (rp side only) + pack h-pairs -> rs/ts
        {
            const int hloc = h0 + lq * 4;     // D rows = hloc..hloc+3
            float4 bv = make_float4(0.f, 0.f, 0.f, 0.f);
            if (wz == 0) bv = *(const float4*)&b1[hc + hloc];
            unsigned* dst = wz ? ts : rs;
            const int hp = hloc >> 1;
            dst[(hp + 0) * 32 + lm]      = pku(acc0[0] + bv.x, acc0[1] + bv.y);
            dst[(hp + 1) * 32 + lm]      = pku(acc0[2] + bv.z, acc0[3] + bv.w);
            dst[(hp + 0) * 32 + 16 + lm] = pku(acc1[0] + bv.x, acc1[1] + bv.y);
            dst[(hp + 1) * 32 + 16 + lm] = pku(acc1[2] + bv.z, acc1[3] + bv.w);
        }
        __syncthreads();

        // ---- score: 32 hp this chunk, wave handles 4 ----
        #pragma unroll
        for (int q = 0; q < 4; ++q) {
            int s = wave * 4 + q;
            uint4 da = *(const uint4*)&rs[s * 32 + 4 * ly];   // broadcast reads
            uint4 dc = *(const uint4*)&ts[s * 32 + 4 * lx];
            float2 wf = *(const float2*)&W2[2 * (it * 32 + s)];
            h2 wv = pk(wf.x, wf.y);
            h2 aa[4] = {u2h(da.x), u2h(da.y), u2h(da.z), u2h(da.w)};
            h2 cc[4] = {u2h(dc.x), u2h(dc.y), u2h(dc.z), u2h(dc.w)};
            #pragma unroll
            for (int i2 = 0; i2 < 4; ++i2)
                #pragma unroll
                for (int j2 = 0; j2 < 4; ++j2) {
                    h2 p = aa[i2] + cc[j2];                        // v_pk_add_f16
                    p = __builtin_elementwise_max(p, hzero);       // v_pk_max_f16
                    sacc[i2][j2] = __builtin_amdgcn_fdot2(p, wv, sacc[i2][j2], false);
                }
        }
        // no barrier here: next iter's barrier (after stage) orders pack-writes
        // vs this score's reads; stage writes Ws which score doesn't touch.
    }

    // ---- epilogue: cross-wave reduce (reuse Ws area), write out ----
    __syncthreads();
    float* red = (float*)smem;            // 8 * 1280 f32 = 40 KB
    {
        float* p = &red[wave * 1280 + lane * 20];
        #pragma unroll
        for (int i2 = 0; i2 < 4; ++i2)
            *(float4*)&p[4 * i2] = make_float4(sacc[i2][0], sacc[i2][1], sacc[i2][2], sacc[i2][3]);
    }
    __syncthreads();
    const float b2v = b2[0];
    #pragma unroll
    for (int half = 0; half < 2; ++half) {
        int j = tid + half * 512;         // 0..1023 outputs
        float sum = 0.f;
        #pragma unroll
        for (int w = 0; w < 8; ++w) sum += red[w * 1280 + (j >> 4) * 20 + (j & 15)];
        int ly2 = j >> 7, lx2 = (j >> 4) & 7, dr = (j >> 2) & 3, dt = j & 3;
        out[(rbase + 4 * ly2 + dr) * RT + tbase + 4 * lx2 + dt] = sum + b2v;
    }
}

extern "C" void kernel_launch(void* const* d_in, const int* in_sizes, int n_in,
                              void* d_out, int out_size, void* d_ws, size_t ws_size,
                              hipStream_t stream) {
    const float* robot = (const float*)d_in[0];
    const float* task  = (const float*)d_in[1];
    const float* W1    = (const float*)d_in[2];
    const float* b1    = (const float*)d_in[3];
    const float* W2    = (const float*)d_in[4];
    const float* b2    = (const float*)d_in[5];
    float* out = (float*)d_out;
    (void)d_ws; (void)ws_size;

    fused<<<dim3(16, 16), 512, 0, stream>>>(robot, task, W1, b1, W2, b2, out);
}

// Round 10
// 20.435 us; speedup vs baseline: 1.6066x; 1.6066x over previous
//
#include <hip/hip_runtime.h>
#include <hip/hip_fp16.h>

// scores[r,t] = b2 + sum_h W2[h] * relu(rp[r,h] + tp[t,h])
//   rp = robot @ W1[:256] + b1 ; tp = task @ W1[256:]
// K1 gemm_packed (512 blk x 256 thr, 2 blk/CU): MFMA f16, A=W1^T staged in LDS
//    (32h x 256k, 16 KB), B=X rows from global. ws packed half2 h-pairs.
// K2 score (256 blk x 512 thr): UNCHANGED from R7 (proven 18.94 config).
// ws: rpP uint[256*512] | tpP uint[256*512]  (1 MB)
// Model: ~7.2us per dispatch overhead; 2 dispatches optimal (1-disp fused
// measured 32.8us: 16x W1 re-read = 7.4us L2-bound + serialization).
// Cooperative launch banned (R6 container deadlock).

#define RT 512
#define DD 256
#define HD 512

typedef _Float16 h2 __attribute__((ext_vector_type(2)));
typedef _Float16 h8 __attribute__((ext_vector_type(8)));
typedef float f32x4 __attribute__((ext_vector_type(4)));

__device__ inline unsigned h2u(h2 v) { return __builtin_bit_cast(unsigned, v); }
__device__ inline h2 u2h(unsigned u) { return __builtin_bit_cast(h2, u); }
__device__ inline h2 pk(float a, float b) {
    return __builtin_bit_cast(h2, __builtin_amdgcn_cvt_pkrtz(a, b));  // v_cvt_pkrtz_f16_f32
}
__device__ inline unsigned pku(float a, float b) { return h2u(pk(a, b)); }

// ---------------- K1: GEMM -> packed half2 ws ----------------
// grid (16 htile, 16 rtile, 2 z), 256 thr (4 waves). Wave: (rhalf, hhalf),
// one 16h x 16r MFMA chain over K=256.
__global__ __launch_bounds__(256) void gemm_packed(
    const float* __restrict__ robot, const float* __restrict__ task,
    const float* __restrict__ W1, const float* __restrict__ b1,
    unsigned* __restrict__ wsu)
{
    __shared__ __attribute__((aligned(16))) unsigned char smem[16384];  // Ws f16 [32h][256k] swz

    const int tid = threadIdx.x;
    const int wave = tid >> 6, lane = tid & 63;
    const int z = blockIdx.z;
    const int rtile = blockIdx.y * 32, htile = blockIdx.x * 32;
    const float* X = z ? task : robot;
    const float* Wz = W1 + z * DD * HD;

    // stage Ws: W1[k][htile+h] -> Ws[h][k] f16, rows 512B, XOR swz ((h&7)<<4)
    {
        const int hh = tid & 31, kg = tid >> 5;        // kg 0..7: k-range kg*32..+32
        #pragma unroll
        for (int j = 0; j < 4; ++j) {
            float f[8];
            #pragma unroll
            for (int u = 0; u < 8; ++u)
                f[u] = Wz[(kg * 32 + j * 8 + u) * HD + htile + hh];
            uint4 o = make_uint4(pku(f[0], f[1]), pku(f[2], f[3]),
                                 pku(f[4], f[5]), pku(f[6], f[7]));
            *(uint4*)(smem + ((hh * 512 + (kg * 32 + j * 8) * 2) ^ ((hh & 7) << 4))) = o;
        }
    }
    __syncthreads();

    const int rhalf = wave >> 1, hhalf = wave & 1;
    const int lm = lane & 15, lq = lane >> 4;
    const int xrow = rtile + rhalf * 16 + lm;
    const float* Xp = &X[xrow * DD];

    f32x4 acc = {0.f, 0.f, 0.f, 0.f};
    #pragma unroll
    for (int ks = 0; ks < 8; ++ks) {
        // B-frag: X[xrow][ks*32 + lq*8 .. +8) from global, f32->f16
        const float* xp = Xp + ks * 32 + lq * 8;
        float4 v0 = *(const float4*)xp, v1 = *(const float4*)(xp + 4);
        uint4 bu = make_uint4(pku(v0.x, v0.y), pku(v0.z, v0.w),
                              pku(v1.x, v1.y), pku(v1.z, v1.w));
        const int ha = hhalf * 16 + lm;
        h8 a = *(const h8*)(smem + ((ha * 512 + ks * 64 + lq * 16) ^ ((ha & 7) << 4)));
        acc = __builtin_amdgcn_mfma_f32_16x16x32_f16(a, __builtin_bit_cast(h8, bu), acc, 0, 0, 0);
    }

    // epilogue: D col(lane&15)=r, rows (lane>>4)*4+j = h; pack h-pairs + bias
    const int hq = htile + hhalf * 16 + lq * 4;
    float4 bv = make_float4(0.f, 0.f, 0.f, 0.f);
    if (z == 0) bv = *(const float4*)&b1[hq];
    unsigned* P = wsu + z * (256 * RT);
    P[((hq >> 1) + 0) * RT + xrow] = pku(acc[0] + bv.x, acc[1] + bv.y);
    P[((hq >> 1) + 1) * RT + xrow] = pku(acc[2] + bv.z, acc[3] + bv.w);
}

// ---------------- K2: score (UNCHANGED from R7) ----------------
// grid (16,16), 512 thr (8 waves), 32x32 out tile, waves split 256 h-pairs.
__global__ __launch_bounds__(512) void score(
    const unsigned* __restrict__ wsu, const float* __restrict__ W2,
    const float* __restrict__ b2, float* __restrict__ out)
{
    __shared__ __attribute__((aligned(16))) unsigned smem[16384];  // 64 KB
    unsigned* rs = smem;            // [256 hp][32 r]
    unsigned* ts = smem + 8192;     // [256 hp][32 t]

    const unsigned* rpP = wsu;
    const unsigned* tpP = wsu + 256 * RT;
    const int tid = threadIdx.x;
    const int rbase = blockIdx.y * 32, tbase = blockIdx.x * 32;

    #pragma unroll
    for (int i = 0; i < 8; ++i) {
        int u = tid + 512 * i;              // 0..4095 uint4-units
        int hp = (u >> 3) & 255, rq = (u & 7) * 4;
        if (u < 2048)
            *(uint4*)&rs[hp * 32 + rq] = *(const uint4*)&rpP[hp * RT + rbase + rq];
        else
            *(uint4*)&ts[hp * 32 + rq] = *(const uint4*)&tpP[hp * RT + tbase + rq];
    }
    __syncthreads();

    const int wave = tid >> 6, lane = tid & 63;
    const int ly = (lane >> 3) & 7, lx = lane & 7;   // 8x8 lanes, 4x4 micro
    const h2 hzero = {};
    float acc[4][4] = {};
    const int s0 = wave * 32;
    #pragma unroll 4
    for (int s = s0; s < s0 + 32; ++s) {
        uint4 da = *(const uint4*)&rs[s * 32 + 4 * ly];   // broadcast, conflict-free
        uint4 dc = *(const uint4*)&ts[s * 32 + 4 * lx];
        float2 wf = *(const float2*)&W2[2 * s];           // uniform -> s_load
        h2 wv = pk(wf.x, wf.y);
        h2 a[4] = {u2h(da.x), u2h(da.y), u2h(da.z), u2h(da.w)};
        h2 c[4] = {u2h(dc.x), u2h(dc.y), u2h(dc.z), u2h(dc.w)};
        #pragma unroll
        for (int i2 = 0; i2 < 4; ++i2)
            #pragma unroll
            for (int j2 = 0; j2 < 4; ++j2) {
                h2 p = a[i2] + c[j2];                          // v_pk_add_f16
                p = __builtin_elementwise_max(p, hzero);       // v_pk_max_f16
                acc[i2][j2] = __builtin_amdgcn_fdot2(p, wv, acc[i2][j2], false);
            }
    }

    __syncthreads();                       // all waves done reading rs/ts
    float* red = (float*)smem;             // 8 * 1280 f32 = 40 KB
    {
        float* p = &red[wave * 1280 + lane * 20];
        #pragma unroll
        for (int i2 = 0; i2 < 4; ++i2)
            *(float4*)&p[4 * i2] = make_float4(acc[i2][0], acc[i2][1], acc[i2][2], acc[i2][3]);
    }
    __syncthreads();
    const float b2v = b2[0];
    #pragma unroll
    for (int half = 0; half < 2; ++half) {
        int j = tid + half * 512;          // 0..1023 output elements
        float sum = 0.f;
        #pragma unroll
        for (int w = 0; w < 8; ++w) sum += red[w * 1280 + (j >> 4) * 20 + (j & 15)];
        int ly2 = j >> 7, lx2 = (j >> 4) & 7, dr = (j >> 2) & 3, dt = j & 3;
        out[(rbase + 4 * ly2 + dr) * RT + tbase + 4 * lx2 + dt] = sum + b2v;
    }
}

extern "C" void kernel_launch(void* const* d_in, const int* in_sizes, int n_in,
                              void* d_out, int out_size, void* d_ws, size_t ws_size,
                              hipStream_t stream) {
    const float* robot = (const float*)d_in[0];
    const float* task  = (const float*)d_in[1];
    const float* W1    = (const float*)d_in[2];
    const float* b1    = (const float*)d_in[3];
    const float* W2    = (const float*)d_in[4];
    const float* b2    = (const float*)d_in[5];
    float* out = (float*)d_out;
    unsigned* wsu = (unsigned*)d_ws;   // 1 MB packed rp/tp

    gemm_packed<<<dim3(16, 16, 2), 256, 0, stream>>>(robot, task, W1, b1, wsu);
    score<<<dim3(16, 16), 512, 0, stream>>>(wsu, W2, b2, out);
}

// Round 12
// 18.956 us; speedup vs baseline: 1.7320x; 1.0780x over previous
//
#include <hip/hip_runtime.h>
#include <hip/hip_fp16.h>

// scores[r,t] = b2 + sum_h W2[h] * relu(rp[r,h] + tp[t,h])
//   rp = robot @ W1[:256] + b1 ; tp = task @ W1[256:]
// BEST-KNOWN CONFIG (R7, 18.94us) — resubmitted unchanged after R11
// infrastructure failure (container unresponsive on first message; this exact
// source ran clean at R7).
// K1 gemm_packed (256 blk x 256 thr): MFMA f16, A=W1^T (M=h) staged in LDS,
//    B=robot/task built per-ks directly from global (16B/lane contiguous).
//    Writes ws as packed half2 h-pairs rpP/tpP [256 hp][512 r], bias folded.
// K2 score (256 blk x 512 thr): pure-copy staging, v_pk_add/max_f16 +
//    v_dot2_f32_f16, 8 waves split 256 h-pairs, in-LDS reduce.
// ws: rpP uint[256*512] | tpP uint[256*512]  (1 MB)
// Model (confirmed R1/R3/R5/R7/R8/R9): ~7.2us/dispatch overhead; 2 dispatches
// optimal; compute ~4.5us at its structural floor (relu blocks MFMA for the
// h-contraction; K2 inner loop is 3 packed ops / 2h, irreducible).
// Cooperative launch banned (R6 container deadlock). 1-disp fused = 32.8us (R9).

#define RT 512
#define DD 256
#define HD 512

typedef _Float16 h2 __attribute__((ext_vector_type(2)));
typedef _Float16 h8 __attribute__((ext_vector_type(8)));
typedef float f32x4 __attribute__((ext_vector_type(4)));

__device__ inline unsigned h2u(h2 v) { return __builtin_bit_cast(unsigned, v); }
__device__ inline h2 u2h(unsigned u) { return __builtin_bit_cast(h2, u); }
__device__ inline h2 pk(float a, float b) {
    return __builtin_bit_cast(h2, __builtin_amdgcn_cvt_pkrtz(a, b));  // v_cvt_pkrtz_f16_f32
}

// ---------------- K1: GEMM -> packed half2 ws ----------------
// Block b: z=b>>7, rtile=(b&15)*32, htile=((b>>4)&7)*64. 4 waves:
// wave>>1 = r-strip (16 rows), wave&1 = h-strip (32 of 64 h).
__global__ __launch_bounds__(256) void gemm_packed(
    const float* __restrict__ robot, const float* __restrict__ task,
    const float* __restrict__ W1, const float* __restrict__ b1,
    unsigned* __restrict__ wsu)
{
    __shared__ __attribute__((aligned(16))) unsigned smem[8192];   // 32 KB
    unsigned short* Ws = (unsigned short*)smem;    // f16 [64 h][256 k], swz

    const int tid = threadIdx.x;
    const int wave = tid >> 6, lane = tid & 63;
    const int b = blockIdx.x;
    const int z = b >> 7, sub = b & 127;
    const int rtile = (sub & 15) * 32;
    const int htile = (sub >> 4) * 64;
    const float* X = z ? task : robot;
    const float* Wz = W1 + z * DD * HD;

    // stage Ws: W1[k][h] -> Ws[h][k] (lane-coalesced in h), f32->f16
    {
        const int hh = tid & 63, k0 = (tid >> 6) * 64;
        #pragma unroll
        for (int j = 0; j < 8; ++j) {
            float f[8];
            #pragma unroll
            for (int u = 0; u < 8; ++u)
                f[u] = Wz[(k0 + 8 * j + u) * HD + htile + hh];
            uint4 o = make_uint4(h2u(pk(f[0], f[1])), h2u(pk(f[2], f[3])),
                                 h2u(pk(f[4], f[5])), h2u(pk(f[6], f[7])));
            *(uint4*)((char*)Ws + ((hh * 512 + k0 * 2 + j * 16) ^ ((hh & 7) << 4))) = o;
        }
    }
    __syncthreads();

    const int wstrip = wave >> 1;          // r-strip
    const int wh = (wave & 1) * 32;        // h-strip base
    const int lm = lane & 15;
    const int lkb = (lane >> 4) * 16;      // k-slice byte offset
    const int xrow = rtile + wstrip * 16 + lm;
    const float* Xp = &X[xrow * DD];

    f32x4 acc0 = {0.f, 0.f, 0.f, 0.f}, acc1 = {0.f, 0.f, 0.f, 0.f};
    #pragma unroll
    for (int ks = 0; ks < 8; ++ks) {
        // B-frag: X[xrow][ks*32 + (lane>>4)*8 .. +8) from global, f32->f16
        const float* xp = Xp + ks * 32 + (lane >> 4) * 8;
        float4 v0 = *(const float4*)xp, v1 = *(const float4*)(xp + 4);
        uint4 bu = make_uint4(h2u(pk(v0.x, v0.y)), h2u(pk(v0.z, v0.w)),
                              h2u(pk(v1.x, v1.y)), h2u(pk(v1.z, v1.w)));
        h8 bb = __builtin_bit_cast(h8, bu);
        const int h0 = wh + lm, h1 = wh + 16 + lm;
        h8 a0 = *(const h8*)((const char*)Ws + ((h0 * 512 + ks * 64 + lkb) ^ ((h0 & 7) << 4)));
        h8 a1 = *(const h8*)((const char*)Ws + ((h1 * 512 + ks * 64 + lkb) ^ ((h1 & 7) << 4)));
        acc0 = __builtin_amdgcn_mfma_f32_16x16x32_f16(a0, bb, acc0, 0, 0, 0);
        acc1 = __builtin_amdgcn_mfma_f32_16x16x32_f16(a1, bb, acc1, 0, 0, 0);
    }

    // epilogue: D col(lane&15)=r, rows (lane>>4)*4+j = h; pack h-pairs
    unsigned* P = wsu + z * (256 * RT);
    const int r = xrow;
    #pragma unroll
    for (int mf = 0; mf < 2; ++mf) {
        f32x4 acc = mf ? acc1 : acc0;
        const int hq = htile + wh + mf * 16 + (lane >> 4) * 4;
        float4 bv = make_float4(0.f, 0.f, 0.f, 0.f);
        if (z == 0) bv = *(const float4*)&b1[hq];
        P[((hq >> 1) + 0) * RT + r] = h2u(pk(acc[0] + bv.x, acc[1] + bv.y));
        P[((hq >> 1) + 1) * RT + r] = h2u(pk(acc[2] + bv.z, acc[3] + bv.w));
    }
}

// ---------------- K2: score ----------------
// grid (16,16), 512 thr (8 waves), 32x32 out tile, waves split 256 h-pairs.
__global__ __launch_bounds__(512) void score(
    const unsigned* __restrict__ wsu, const float* __restrict__ W2,
    const float* __restrict__ b2, float* __restrict__ out)
{
    __shared__ __attribute__((aligned(16))) unsigned smem[16384];  // 64 KB
    unsigned* rs = smem;            // [256 hp][32 r]
    unsigned* ts = smem + 8192;     // [256 hp][32 t]

    const unsigned* rpP = wsu;
    const unsigned* tpP = wsu + 256 * RT;
    const int tid = threadIdx.x;
    const int rbase = blockIdx.y * 32, tbase = blockIdx.x * 32;

    #pragma unroll
    for (int i = 0; i < 8; ++i) {
        int u = tid + 512 * i;              // 0..4095 uint4-units
        int hp = (u >> 3) & 255, rq = (u & 7) * 4;
        if (u < 2048)
            *(uint4*)&rs[hp * 32 + rq] = *(const uint4*)&rpP[hp * RT + rbase + rq];
        else
            *(uint4*)&ts[hp * 32 + rq] = *(const uint4*)&tpP[hp * RT + tbase + rq];
    }
    __syncthreads();

    const int wave = tid >> 6, lane = tid & 63;
    const int ly = (lane >> 3) & 7, lx = lane & 7;   // 8x8 lanes, 4x4 micro
    const h2 hzero = {};
    float acc[4][4] = {};
    const int s0 = wave * 32;
    #pragma unroll 4
    for (int s = s0; s < s0 + 32; ++s) {
        uint4 da = *(const uint4*)&rs[s * 32 + 4 * ly];   // broadcast, conflict-free
        uint4 dc = *(const uint4*)&ts[s * 32 + 4 * lx];
        float2 wf = *(const float2*)&W2[2 * s];           // uniform -> s_load
        h2 wv = pk(wf.x, wf.y);
        h2 a[4] = {u2h(da.x), u2h(da.y), u2h(da.z), u2h(da.w)};
        h2 c[4] = {u2h(dc.x), u2h(dc.y), u2h(dc.z), u2h(dc.w)};
        #pragma unroll
        for (int i2 = 0; i2 < 4; ++i2)
            #pragma unroll
            for (int j2 = 0; j2 < 4; ++j2) {
                h2 p = a[i2] + c[j2];                          // v_pk_add_f16
                p = __builtin_elementwise_max(p, hzero);       // v_pk_max_f16
                acc[i2][j2] = __builtin_amdgcn_fdot2(p, wv, acc[i2][j2], false);
            }
    }

    __syncthreads();                       // all waves done reading rs/ts
    float* red = (float*)smem;             // 8 * 1280 f32 = 40 KB
    {
        float* p = &red[wave * 1280 + lane * 20];
        #pragma unroll
        for (int i2 = 0; i2 < 4; ++i2)
            *(float4*)&p[4 * i2] = make_float4(acc[i2][0], acc[i2][1], acc[i2][2], acc[i2][3]);
    }
    __syncthreads();
    const float b2v = b2[0];
    #pragma unroll
    for (int half = 0; half < 2; ++half) {
        int j = tid + half * 512;          // 0..1023 output elements
        float sum = 0.f;
        #pragma unroll
        for (int w = 0; w < 8; ++w) sum += red[w * 1280 + (j >> 4) * 20 + (j & 15)];
        int ly2 = j >> 7, lx2 = (j >> 4) & 7, dr = (j >> 2) & 3, dt = j & 3;
        out[(rbase + 4 * ly2 + dr) * RT + tbase + 4 * lx2 + dt] = sum + b2v;
    }
}

extern "C" void kernel_launch(void* const* d_in, const int* in_sizes, int n_in,
                              void* d_out, int out_size, void* d_ws, size_t ws_size,
                              hipStream_t stream) {
    const float* robot = (const float*)d_in[0];
    const float* task  = (const float*)d_in[1];
    const float* W1    = (const float*)d_in[2];
    const float* b1    = (const float*)d_in[3];
    const float* W2    = (const float*)d_in[4];
    const float* b2    = (const float*)d_in[5];
    float* out = (float*)d_out;
    unsigned* wsu = (unsigned*)d_ws;   // 1 MB packed rp/tp

    gemm_packed<<<dim3(256), 256, 0, stream>>>(robot, task, W1, b1, wsu);
    score<<<dim3(16, 16), 512, 0, stream>>>(wsu, W2, b2, out);
}